// Round 3
// baseline (219.736 us; speedup 1.0000x reference)
//
#include <hip/hip_runtime.h>
#include <stdint.h>

// SeqAttnMatch: B=32, LP=2048, LQ=512, D=256, fp32 in/out. Single-plane fp16 pipeline.
#define B_  32
#define LP_ 2048
#define LQ_ 512
#define D_  256

typedef __attribute__((ext_vector_type(8))) short short8;      // 8 x 16-bit
typedef __attribute__((ext_vector_type(8))) _Float16 f16x8;    // MFMA A/B frag (4 VGPRs)
typedef __attribute__((ext_vector_type(4))) float f32x4;

__device__ __forceinline__ ushort f2h(float x) {
    union { _Float16 h; ushort u; } v;
    v.h = (_Float16)x;                 // RNE convert
    return v.u;
}
// async global->LDS, 16B/lane; HW writes lds_base + lane*16 (wave-uniform base).
__device__ __forceinline__ void gl_lds16(const void* g, void* l) {
    __builtin_amdgcn_global_load_lds(
        (const __attribute__((address_space(1))) void*)g,
        (__attribute__((address_space(3))) void*)l, 16, 0, 0);
}

// Fragment-blocked layout: 1KB blocks of 512 ushorts. Element for lane
// L=quad*16+c, position L*8 + j, holds M[row_tile*16 + c][k0 + quad*8 + j].

// ---- K0: fused W f32->f16 frag convert (blocks 0..255) + y transpose (256..767) ----
// W block (kc=k/32, nt=e/16) at kc*16+nt. y block (b, qc=q/32, nt=d/16) at b*256+qc*16+nt,
// lane (c,quad,j) = y[qc*32+quad*8+j][nt*16+c] (Phase-C B operand: k=q, n=d).
__global__ void k_prep(const float* __restrict__ W, const float* __restrict__ y,
                       ushort* __restrict__ Whf, ushort* __restrict__ yf) {
    __shared__ float t[32 * 260];
    if (blockIdx.x < 256) {
        int i = blockIdx.x * 256 + threadIdx.x;
        int e = i >> 8, k = i & 255;
        size_t off = (size_t)((k >> 5) * 16 + (e >> 4)) * 512 +
                     ((k >> 3) & 3) * 128 + (e & 15) * 8 + (k & 7);
        Whf[off] = f2h(W[i]);
        return;
    }
    int bid = blockIdx.x - 256;      // 512 blocks
    int b = bid >> 4, qc = bid & 15;
    int tid = threadIdx.x;
    int ql = tid >> 3;               // 0..31
    int d0 = (tid & 7) * 4;
#pragma unroll
    for (int p = 0; p < 8; p++) {
        int d = p * 32 + d0;
        float4 v = *(const float4*)(y + ((size_t)(b * LQ_ + qc * 32 + ql) * 256 + d));
        t[ql * 260 + d + 0] = v.x; t[ql * 260 + d + 1] = v.y;
        t[ql * 260 + d + 2] = v.z; t[ql * 260 + d + 3] = v.w;
    }
    __syncthreads();
    int w = tid >> 6, L = tid & 63, c = L & 15, quad = L >> 4;
#pragma unroll
    for (int ii = 0; ii < 4; ii++) {
        int nt = w * 4 + ii;
        short8 o;
#pragma unroll
        for (int j = 0; j < 8; j++)
            o[j] = (short)f2h(t[(quad * 8 + j) * 260 + nt * 16 + c]);
        *(short8*)(yf + ((size_t)(b * 256 + qc * 16 + nt) * 512 + L * 8)) = o;
    }
}

// ---- K1: proj = relu(A @ W^T + b) -> frag-blocked f16, single plane ----
// 1280 blocks: 0..255 y-proj, 256..1279 x-proj. 256 thr (4 waves), 64 rows/block.
// x layout: block = rt_g*8 + ec. y layout: (rt_g>>5)*256 + ec*32 + (rt_g&31).
__global__ __launch_bounds__(256, 3) void k_proj(const float* __restrict__ x,
                                                 const float* __restrict__ y,
                                                 const ushort* __restrict__ Whf,
                                                 const float* __restrict__ bias,
                                                 ushort* __restrict__ Ox,
                                                 ushort* __restrict__ Oy) {
    __shared__ __align__(16) ushort Ws[16704];   // 32KB ping-pong, then 33.3KB transpose
    const int tid  = threadIdx.x;
    const int w    = tid >> 6;
    const int L    = tid & 63;
    const int c    = L & 15;
    const int quad = L >> 4;
    const bool isY = blockIdx.x < 256;
    const float* A = isY ? y : x;
    ushort* O      = isY ? Oy : Ox;
    const int blk0 = isY ? blockIdx.x : (blockIdx.x - 256);
    const int row0 = blk0 * 64 + w * 16;
    const int arow = row0 + c;

    f32x4 acc[16];
#pragma unroll
    for (int i = 0; i < 16; i++) acc[i] = (f32x4)0.f;

    // stage unit kc: 16KB W slab (16 x 1KB units), contiguous DMA, 4 units/wave
#define PSTAGE(kc, p)                                                          \
    {                                                                          \
        _Pragma("unroll")                                                      \
        for (int ii = 0; ii < 4; ii++) {                                       \
            int i = w * 4 + ii;                                                \
            gl_lds16(Whf + (size_t)(kc) * 8192 + i * 512 + L * 8,              \
                     (char*)Ws + (p) * 16384 + i * 1024);                      \
        }                                                                      \
    }

    PSTAGE(0, 0);
    float4 nx0 = *(const float4*)(A + (size_t)arow * 256 + quad * 8);
    float4 nx1 = *(const float4*)(A + (size_t)arow * 256 + quad * 8 + 4);

    for (int kc = 0; kc < 8; kc++) {
        __syncthreads();
        if (kc < 7) PSTAGE(kc + 1, (kc + 1) & 1);
        float4 cx0 = nx0, cx1 = nx1;
        if (kc < 7) {
            nx0 = *(const float4*)(A + (size_t)arow * 256 + (kc + 1) * 32 + quad * 8);
            nx1 = *(const float4*)(A + (size_t)arow * 256 + (kc + 1) * 32 + quad * 8 + 4);
        }
        float xs[8] = {cx0.x, cx0.y, cx0.z, cx0.w, cx1.x, cx1.y, cx1.z, cx1.w};
        f16x8 ah;
#pragma unroll
        for (int j = 0; j < 8; j++) ah[j] = (_Float16)xs[j];
        const ushort* buf = Ws + (kc & 1) * 8192;
#pragma unroll
        for (int nt = 0; nt < 16; nt++) {
            f16x8 bh = *(const f16x8*)(buf + nt * 512 + L * 8);
            acc[nt] = __builtin_amdgcn_mfma_f32_16x16x32_f16(ah, bh, acc[nt], 0, 0, 0);
        }
    }

    // epilogue: bias+relu, per-wave LDS transpose C-layout -> A-frag layout
    __syncthreads();                 // all waves done reading Ws
    float* tr = (float*)Ws + w * (16 * 130);
    const int rt_g = row0 >> 4;
#pragma unroll
    for (int half = 0; half < 2; half++) {
#pragma unroll
        for (int nt8 = 0; nt8 < 8; nt8++) {
            int nt = half * 8 + nt8;
            float bv = bias[nt * 16 + c];
#pragma unroll
            for (int r = 0; r < 4; r++)
                tr[(quad * 4 + r) * 130 + nt8 * 16 + c] = fmaxf(acc[nt][r] + bv, 0.f);
        }
#pragma unroll
        for (int ec4 = 0; ec4 < 4; ec4++) {
            int ec = half * 4 + ec4;
            short8 hh;
#pragma unroll
            for (int j = 0; j < 8; j++)
                hh[j] = (short)f2h(tr[c * 130 + ec4 * 32 + quad * 8 + j]);
            size_t blk = isY ? ((size_t)(rt_g >> 5) * 256 + ec * 32 + (rt_g & 31))
                             : ((size_t)rt_g * 8 + ec);
            *(short8*)(O + blk * 512 + L * 8) = hh;
        }
    }
}

// ---- K2: fused scores (f16) + softmax + match (f16). 32 rows/block, 2048 blocks. ----
// Phase A: wave w = q-quarter w, ALL 32 rows, barrier-free, 1-deep reg prefetch of
// y-frags (16 MFMAs = ~310 SIMD-cyc cover the ~300-cyc L2 latency).
// Phase C: all waves sweep full q, wave w = d-quarter; pairwise kcq with 8-frag prefetch.
__global__ __launch_bounds__(256, 3) void k_attn(const ushort* __restrict__ xpf,
                                                 const ushort* __restrict__ ypf,
                                                 const ushort* __restrict__ yf,
                                                 float* __restrict__ out) {
    __shared__ __align__(16) ushort lds[16384];   // 32KB
    const int tid  = threadIdx.x;
    const int w    = tid >> 6;
    const int L    = tid & 63;
    const int c    = L & 15;
    const int quad = L >> 4;

    // XCD-affinity swizzle: XCD x sees only batches 4x..4x+3
    const int bid = blockIdx.x;
    const int jj  = bid >> 3;
    const int b   = (bid & 7) * 4 + (jj >> 6);
    const int mt  = jj & 63;                       // 0..63, 32 rows each
    const int m0  = mt * 32;

    // ---- stage x-frags: 16 units (rs*8+kc) x 1KB, contiguous DMA ----
#pragma unroll
    for (int ii = 0; ii < 4; ii++) {
        int unit = w * 4 + ii;
        int rs = unit >> 3, kc = unit & 7;
        gl_lds16(xpf + ((size_t)(b * 128 + mt * 2 + rs) * 8 + kc) * 512 + L * 8,
                 (char*)lds + unit * 1024);
    }

    f32x4 sc[2][8];
#pragma unroll
    for (int rs = 0; rs < 2; rs++)
#pragma unroll
        for (int qt = 0; qt < 8; qt++) sc[rs][qt] = (f32x4)0.f;
    __syncthreads();                 // x-frags visible; ONLY barrier before softmax

    // ---- Phase A: barrier-free; y-frags from L2 with 1-kc register lookahead ----
    const ushort* yb = ypf + (size_t)b * 256 * 512;
    f16x8 bhn[8];
#pragma unroll
    for (int qt = 0; qt < 8; qt++)
        bhn[qt] = *(const f16x8*)(yb + (size_t)(w * 8 + qt) * 512 + L * 8);
    for (int kc = 0; kc < 8; kc++) {
        f16x8 bhc[8];
#pragma unroll
        for (int qt = 0; qt < 8; qt++) bhc[qt] = bhn[qt];
        if (kc < 7) {
#pragma unroll
            for (int qt = 0; qt < 8; qt++)
                bhn[qt] = *(const f16x8*)(yb + ((size_t)(kc + 1) * 32 + w * 8 + qt) * 512 + L * 8);
        }
        f16x8 ah0 = *(const f16x8*)(lds + kc * 512 + L * 8);
        f16x8 ah1 = *(const f16x8*)(lds + (8 + kc) * 512 + L * 8);
#pragma unroll
        for (int qt = 0; qt < 8; qt++) {
            sc[0][qt] = __builtin_amdgcn_mfma_f32_16x16x32_f16(ah0, bhc[qt], sc[0][qt], 0, 0, 0);
            sc[1][qt] = __builtin_amdgcn_mfma_f32_16x16x32_f16(ah1, bhc[qt], sc[1][qt], 0, 0, 0);
        }
    }

    // ---- Phase B: softmax; each wave holds a q-quarter of every row ----
    __syncthreads();                 // x-frag reads done; lds reusable
    float* red  = (float*)lds;       // [32][4] partial max
    float* red2 = red + 128;         // [32][4] partial sum
    float inv[2][4];
#pragma unroll
    for (int rs = 0; rs < 2; rs++)
#pragma unroll
        for (int r = 0; r < 4; r++) {
            float pm = sc[rs][0][r];
#pragma unroll
            for (int qt = 1; qt < 8; qt++) pm = fmaxf(pm, sc[rs][qt][r]);
#pragma unroll
            for (int mask = 1; mask <= 8; mask <<= 1) pm = fmaxf(pm, __shfl_xor(pm, mask));
            if (c == 0) red[(rs * 16 + quad * 4 + r) * 4 + w] = pm;
        }
    __syncthreads();
#pragma unroll
    for (int rs = 0; rs < 2; rs++)
#pragma unroll
        for (int r = 0; r < 4; r++) {
            int row = rs * 16 + quad * 4 + r;
            float m = fmaxf(fmaxf(red[row * 4], red[row * 4 + 1]),
                            fmaxf(red[row * 4 + 2], red[row * 4 + 3]));
            float ps = 0.f;
#pragma unroll
            for (int qt = 0; qt < 8; qt++) {
                float e = __expf(sc[rs][qt][r] - m);
                sc[rs][qt][r] = e;
                ps += e;
            }
#pragma unroll
            for (int mask = 1; mask <= 8; mask <<= 1) ps += __shfl_xor(ps, mask);
            if (c == 0) red2[row * 4 + w] = ps;
        }
    __syncthreads();
#pragma unroll
    for (int rs = 0; rs < 2; rs++)
#pragma unroll
        for (int r = 0; r < 4; r++) {
            int row = rs * 16 + quad * 4 + r;
            inv[rs][r] = 1.f / (red2[row * 4] + red2[row * 4 + 1] +
                                red2[row * 4 + 2] + red2[row * 4 + 3]);
        }
    __syncthreads();                 // red/red2 reads done before alpha overwrites

    // alpha (f16) -> LDS [32 rows][512 q], xor-swizzled 8-elem chunks
#pragma unroll
    for (int rs = 0; rs < 2; rs++)
#pragma unroll
        for (int r = 0; r < 4; r++) {
            int m_loc = rs * 16 + quad * 4 + r;
            int swz = m_loc & 7;
            float iv = inv[rs][r];
#pragma unroll
            for (int qt = 0; qt < 8; qt++) {
                int q = w * 128 + qt * 16 + c;
                lds[m_loc * 512 + (((q >> 3) ^ swz) << 3) + (c & 7)] = f2h(sc[rs][qt][r] * iv);
            }
        }
    __syncthreads();

    // ---- Phase C: out = alpha(LDS) @ yf(global). wave w = d-quarter, full q sweep. ----
    // Pairwise kcq: prefetch next pair's 8 y-frags under current pair's 16 MFMAs.
    f32x4 o[2][4];
#pragma unroll
    for (int rs = 0; rs < 2; rs++)
#pragma unroll
        for (int dt = 0; dt < 4; dt++) o[rs][dt] = (f32x4)0.f;
    const int dh = w;
    const int swzA = c & 7;          // (rs*16+c)&7 == c&7
    f16x8 bfn[8];
#pragma unroll
    for (int u = 0; u < 8; u++)
        bfn[u] = *(const f16x8*)(yf + (size_t)(b * 256 + (u >> 2) * 16 + dh * 4 + (u & 3)) * 512 + L * 8);
    for (int kp = 0; kp < 8; kp++) {           // pair kcq = 2*kp, 2*kp+1
        f16x8 bfc[8];
#pragma unroll
        for (int u = 0; u < 8; u++) bfc[u] = bfn[u];
        if (kp < 7) {
#pragma unroll
            for (int u = 0; u < 8; u++)
                bfn[u] = *(const f16x8*)(yf + (size_t)(b * 256 + (2 * kp + 2 + (u >> 2)) * 16 + dh * 4 + (u & 3)) * 512 + L * 8);
        }
#pragma unroll
        for (int h = 0; h < 2; h++) {
            int kcq = 2 * kp + h;
            int chunk = kcq * 4 + quad;
            f16x8 af0 = *(const f16x8*)(lds + c * 512 + ((chunk ^ swzA) << 3));
            f16x8 af1 = *(const f16x8*)(lds + (16 + c) * 512 + ((chunk ^ swzA) << 3));
#pragma unroll
            for (int dt = 0; dt < 4; dt++) {
                o[0][dt] = __builtin_amdgcn_mfma_f32_16x16x32_f16(af0, bfc[h * 4 + dt], o[0][dt], 0, 0, 0);
                o[1][dt] = __builtin_amdgcn_mfma_f32_16x16x32_f16(af1, bfc[h * 4 + dt], o[1][dt], 0, 0, 0);
            }
        }
    }

    // ---- direct store (no exchange: each wave owns a d-quarter, full q summed) ----
#pragma unroll
    for (int rs = 0; rs < 2; rs++)
#pragma unroll
        for (int dt = 0; dt < 4; dt++)
#pragma unroll
            for (int r = 0; r < 4; r++) {
                int row = rs * 16 + quad * 4 + r;
                out[(size_t)(b * LP_ + m0 + row) * 256 + dh * 64 + dt * 16 + c] =
                    o[rs][dt][r];
            }
}

extern "C" void kernel_launch(void* const* d_in, const int* in_sizes, int n_in,
                              void* d_out, int out_size, void* d_ws, size_t ws_size,
                              hipStream_t stream) {
    const float* x    = (const float*)d_in[0];
    const float* y    = (const float*)d_in[1];
    const float* W    = (const float*)d_in[2];
    const float* bias = (const float*)d_in[3];
    float* out = (float*)d_out;

    char* ws = (char*)d_ws;
    size_t off = 0;
    ushort* Whf = (ushort*)(ws + off); off += (size_t)D_ * D_ * 2;          // 128KB
    ushort* yfb = (ushort*)(ws + off); off += (size_t)B_ * D_ * LQ_ * 2;    // 8MB
    ushort* ypf = (ushort*)(ws + off); off += (size_t)B_ * LQ_ * D_ * 2;    // 8MB
    ushort* xpf = (ushort*)(ws + off); off += (size_t)B_ * LP_ * D_ * 2;    // 32MB

    k_prep<<<768, 256, 0, stream>>>(W, y, Whf, yfb);
    k_proj<<<1280, 256, 0, stream>>>(x, y, Whf, bias, xpf, ypf);
    k_attn<<<B_ * 64, 256, 0, stream>>>(xpf, ypf, yfb, out);
}

// Round 4
// 204.383 us; speedup vs baseline: 1.0751x; 1.0751x over previous
//
#include <hip/hip_runtime.h>
#include <stdint.h>

// SeqAttnMatch: B=32, LP=2048, LQ=512, D=256, fp32 in/out. Single-plane fp16 pipeline.
#define B_  32
#define LP_ 2048
#define LQ_ 512
#define D_  256

typedef __attribute__((ext_vector_type(8))) short short8;      // 8 x 16-bit
typedef __attribute__((ext_vector_type(8))) _Float16 f16x8;    // MFMA A/B frag (4 VGPRs)
typedef __attribute__((ext_vector_type(4))) float f32x4;

__device__ __forceinline__ ushort f2h(float x) {
    union { _Float16 h; ushort u; } v;
    v.h = (_Float16)x;                 // RNE convert
    return v.u;
}
// async global->LDS, 16B/lane; HW writes lds_base + lane*16 (wave-uniform base).
__device__ __forceinline__ void gl_lds16(const void* g, void* l) {
    __builtin_amdgcn_global_load_lds(
        (const __attribute__((address_space(1))) void*)g,
        (__attribute__((address_space(3))) void*)l, 16, 0, 0);
}

// Fragment-blocked layout: 1KB blocks of 512 ushorts. Element for lane
// L=quad*16+c, position L*8 + j, holds M[row_tile*16 + c][k0 + quad*8 + j].

// ---- K0: fused W f32->f16 frag convert (blocks 0..255) + y transpose (256..767) ----
// W block (kc=k/32, nt=e/16) at kc*16+nt. y block (b, qc=q/32, nt=d/16) at b*256+qc*16+nt,
// lane (c,quad,j) = y[qc*32+quad*8+j][nt*16+c] (Phase-C B operand: k=q, n=d).
__global__ void k_prep(const float* __restrict__ W, const float* __restrict__ y,
                       ushort* __restrict__ Whf, ushort* __restrict__ yf) {
    __shared__ float t[32 * 260];
    if (blockIdx.x < 256) {
        int i = blockIdx.x * 256 + threadIdx.x;
        int e = i >> 8, k = i & 255;
        size_t off = (size_t)((k >> 5) * 16 + (e >> 4)) * 512 +
                     ((k >> 3) & 3) * 128 + (e & 15) * 8 + (k & 7);
        Whf[off] = f2h(W[i]);
        return;
    }
    int bid = blockIdx.x - 256;      // 512 blocks
    int b = bid >> 4, qc = bid & 15;
    int tid = threadIdx.x;
    int ql = tid >> 3;               // 0..31
    int d0 = (tid & 7) * 4;
#pragma unroll
    for (int p = 0; p < 8; p++) {
        int d = p * 32 + d0;
        float4 v = *(const float4*)(y + ((size_t)(b * LQ_ + qc * 32 + ql) * 256 + d));
        t[ql * 260 + d + 0] = v.x; t[ql * 260 + d + 1] = v.y;
        t[ql * 260 + d + 2] = v.z; t[ql * 260 + d + 3] = v.w;
    }
    __syncthreads();
    int w = tid >> 6, L = tid & 63, c = L & 15, quad = L >> 4;
#pragma unroll
    for (int ii = 0; ii < 4; ii++) {
        int nt = w * 4 + ii;
        short8 o;
#pragma unroll
        for (int j = 0; j < 8; j++)
            o[j] = (short)f2h(t[(quad * 8 + j) * 260 + nt * 16 + c]);
        *(short8*)(yf + ((size_t)(b * 256 + qc * 16 + nt) * 512 + L * 8)) = o;
    }
}

// ---- K1: proj = relu(A @ W^T + b) -> frag-blocked f16, single plane ----
// 1280 blocks: 0..255 y-proj, 256..1279 x-proj. 256 thr (4 waves), 64 rows/block.
// x layout: block = rt_g*8 + ec. y layout: (rt_g>>5)*256 + ec*32 + (rt_g&31).
__global__ __launch_bounds__(256, 3) void k_proj(const float* __restrict__ x,
                                                 const float* __restrict__ y,
                                                 const ushort* __restrict__ Whf,
                                                 const float* __restrict__ bias,
                                                 ushort* __restrict__ Ox,
                                                 ushort* __restrict__ Oy) {
    __shared__ __align__(16) ushort Ws[16704];   // 32KB ping-pong, then 33.3KB transpose
    const int tid  = threadIdx.x;
    const int w    = tid >> 6;
    const int L    = tid & 63;
    const int c    = L & 15;
    const int quad = L >> 4;
    const bool isY = blockIdx.x < 256;
    const float* A = isY ? y : x;
    ushort* O      = isY ? Oy : Ox;
    const int blk0 = isY ? blockIdx.x : (blockIdx.x - 256);
    const int row0 = blk0 * 64 + w * 16;
    const int arow = row0 + c;

    f32x4 acc[16];
#pragma unroll
    for (int i = 0; i < 16; i++) acc[i] = (f32x4)0.f;

    // stage unit kc: 16KB W slab (16 x 1KB units), contiguous DMA, 4 units/wave
#define PSTAGE(kc, p)                                                          \
    {                                                                          \
        _Pragma("unroll")                                                      \
        for (int ii = 0; ii < 4; ii++) {                                       \
            int i = w * 4 + ii;                                                \
            gl_lds16(Whf + (size_t)(kc) * 8192 + i * 512 + L * 8,              \
                     (char*)Ws + (p) * 16384 + i * 1024);                      \
        }                                                                      \
    }

    PSTAGE(0, 0);
    float4 nx0 = *(const float4*)(A + (size_t)arow * 256 + quad * 8);
    float4 nx1 = *(const float4*)(A + (size_t)arow * 256 + quad * 8 + 4);

    for (int kc = 0; kc < 8; kc++) {
        __syncthreads();
        if (kc < 7) PSTAGE(kc + 1, (kc + 1) & 1);
        float4 cx0 = nx0, cx1 = nx1;
        if (kc < 7) {
            nx0 = *(const float4*)(A + (size_t)arow * 256 + (kc + 1) * 32 + quad * 8);
            nx1 = *(const float4*)(A + (size_t)arow * 256 + (kc + 1) * 32 + quad * 8 + 4);
        }
        float xs[8] = {cx0.x, cx0.y, cx0.z, cx0.w, cx1.x, cx1.y, cx1.z, cx1.w};
        f16x8 ah;
#pragma unroll
        for (int j = 0; j < 8; j++) ah[j] = (_Float16)xs[j];
        const ushort* buf = Ws + (kc & 1) * 8192;
#pragma unroll
        for (int nt = 0; nt < 16; nt++) {
            f16x8 bh = *(const f16x8*)(buf + nt * 512 + L * 8);
            acc[nt] = __builtin_amdgcn_mfma_f32_16x16x32_f16(ah, bh, acc[nt], 0, 0, 0);
        }
    }

    // epilogue: bias+relu, per-wave LDS transpose C-layout -> A-frag layout
    __syncthreads();                 // all waves done reading Ws
    float* tr = (float*)Ws + w * (16 * 130);
    const int rt_g = row0 >> 4;
#pragma unroll
    for (int half = 0; half < 2; half++) {
#pragma unroll
        for (int nt8 = 0; nt8 < 8; nt8++) {
            int nt = half * 8 + nt8;
            float bv = bias[nt * 16 + c];
#pragma unroll
            for (int r = 0; r < 4; r++)
                tr[(quad * 4 + r) * 130 + nt8 * 16 + c] = fmaxf(acc[nt][r] + bv, 0.f);
        }
#pragma unroll
        for (int ec4 = 0; ec4 < 4; ec4++) {
            int ec = half * 4 + ec4;
            short8 hh;
#pragma unroll
            for (int j = 0; j < 8; j++)
                hh[j] = (short)f2h(tr[c * 130 + ec4 * 32 + quad * 8 + j]);
            size_t blk = isY ? ((size_t)(rt_g >> 5) * 256 + ec * 32 + (rt_g & 31))
                             : ((size_t)rt_g * 8 + ec);
            *(short8*)(O + blk * 512 + L * 8) = hh;
        }
    }
}

// ---- K2: fused scores (f16) + softmax + match (f16). 32 rows/block, 2048 blocks. ----
// Phase A: wave w = q-quarter w, ALL 32 rows, barrier-free; x-frags in LDS (16KB).
// Phase C: all waves sweep full q, wave w = d-quarter -> no partial-sum exchange.
// launch_bounds(256,4): force total regs <=128 (64 arch + 64 acc) -> 4 blocks/CU.
__global__ __launch_bounds__(256, 4) void k_attn(const ushort* __restrict__ xpf,
                                                 const ushort* __restrict__ ypf,
                                                 const ushort* __restrict__ yf,
                                                 float* __restrict__ out) {
    __shared__ __align__(16) ushort lds[16384];   // 32KB
    const int tid  = threadIdx.x;
    const int w    = tid >> 6;
    const int L    = tid & 63;
    const int c    = L & 15;
    const int quad = L >> 4;

    // XCD-affinity swizzle: XCD x sees only batches 4x..4x+3
    const int bid = blockIdx.x;
    const int jj  = bid >> 3;
    const int b   = (bid & 7) * 4 + (jj >> 6);
    const int mt  = jj & 63;                       // 0..63, 32 rows each
    const int m0  = mt * 32;

    // ---- stage x-frags: 16 units (rs*8+kc) x 1KB, contiguous DMA ----
#pragma unroll
    for (int ii = 0; ii < 4; ii++) {
        int unit = w * 4 + ii;
        int rs = unit >> 3, kc = unit & 7;
        gl_lds16(xpf + ((size_t)(b * 128 + mt * 2 + rs) * 8 + kc) * 512 + L * 8,
                 (char*)lds + unit * 1024);
    }

    f32x4 sc[2][8];
#pragma unroll
    for (int rs = 0; rs < 2; rs++)
#pragma unroll
        for (int qt = 0; qt < 8; qt++) sc[rs][qt] = (f32x4)0.f;
    __syncthreads();                 // x-frags visible; ONLY barrier before softmax

    // ---- Phase A: barrier-free; B-frags coalesced from L2-resident ypf ----
    const ushort* yb = ypf + (size_t)b * 256 * 512;
    for (int kc = 0; kc < 8; kc++) {
        f16x8 ah0 = *(const f16x8*)(lds + kc * 512 + L * 8);
        f16x8 ah1 = *(const f16x8*)(lds + (8 + kc) * 512 + L * 8);
#pragma unroll
        for (int qt = 0; qt < 8; qt++) {
            f16x8 bh = *(const f16x8*)(yb + ((size_t)kc * 32 + w * 8 + qt) * 512 + L * 8);
            sc[0][qt] = __builtin_amdgcn_mfma_f32_16x16x32_f16(ah0, bh, sc[0][qt], 0, 0, 0);
            sc[1][qt] = __builtin_amdgcn_mfma_f32_16x16x32_f16(ah1, bh, sc[1][qt], 0, 0, 0);
        }
    }

    // ---- Phase B: softmax; each wave holds a q-quarter of every row ----
    __syncthreads();                 // x-frag reads done; lds reusable
    float* red  = (float*)lds;       // [32][4] partial max
    float* red2 = red + 128;         // [32][4] partial sum
    float inv[2][4];
#pragma unroll
    for (int rs = 0; rs < 2; rs++)
#pragma unroll
        for (int r = 0; r < 4; r++) {
            float pm = sc[rs][0][r];
#pragma unroll
            for (int qt = 1; qt < 8; qt++) pm = fmaxf(pm, sc[rs][qt][r]);
#pragma unroll
            for (int mask = 1; mask <= 8; mask <<= 1) pm = fmaxf(pm, __shfl_xor(pm, mask));
            if (c == 0) red[(rs * 16 + quad * 4 + r) * 4 + w] = pm;
        }
    __syncthreads();
#pragma unroll
    for (int rs = 0; rs < 2; rs++)
#pragma unroll
        for (int r = 0; r < 4; r++) {
            int row = rs * 16 + quad * 4 + r;
            float m = fmaxf(fmaxf(red[row * 4], red[row * 4 + 1]),
                            fmaxf(red[row * 4 + 2], red[row * 4 + 3]));
            float ps = 0.f;
#pragma unroll
            for (int qt = 0; qt < 8; qt++) {
                float e = __expf(sc[rs][qt][r] - m);
                sc[rs][qt][r] = e;
                ps += e;
            }
#pragma unroll
            for (int mask = 1; mask <= 8; mask <<= 1) ps += __shfl_xor(ps, mask);
            if (c == 0) red2[row * 4 + w] = ps;
        }
    __syncthreads();
#pragma unroll
    for (int rs = 0; rs < 2; rs++)
#pragma unroll
        for (int r = 0; r < 4; r++) {
            int row = rs * 16 + quad * 4 + r;
            inv[rs][r] = 1.f / (red2[row * 4] + red2[row * 4 + 1] +
                                red2[row * 4 + 2] + red2[row * 4 + 3]);
        }
    __syncthreads();                 // red/red2 reads done before alpha overwrites

    // alpha (f16) -> LDS [32 rows][512 q], xor-swizzled 8-elem chunks
#pragma unroll
    for (int rs = 0; rs < 2; rs++)
#pragma unroll
        for (int r = 0; r < 4; r++) {
            int m_loc = rs * 16 + quad * 4 + r;
            int swz = m_loc & 7;
            float iv = inv[rs][r];
#pragma unroll
            for (int qt = 0; qt < 8; qt++) {
                int q = w * 128 + qt * 16 + c;
                lds[m_loc * 512 + (((q >> 3) ^ swz) << 3) + (c & 7)] = f2h(sc[rs][qt][r] * iv);
            }
        }
    __syncthreads();

    // ---- Phase C: out = alpha(LDS) @ yf(global). wave w = d-quarter, full q sweep. ----
    f32x4 o[2][4];
#pragma unroll
    for (int rs = 0; rs < 2; rs++)
#pragma unroll
        for (int dt = 0; dt < 4; dt++) o[rs][dt] = (f32x4)0.f;
    const int dh = w;
    const int swzA = c & 7;          // (rs*16+c)&7 == c&7
    for (int kcq = 0; kcq < 16; kcq++) {
        int chunk = kcq * 4 + quad;
        f16x8 af0 = *(const f16x8*)(lds + c * 512 + ((chunk ^ swzA) << 3));
        f16x8 af1 = *(const f16x8*)(lds + (16 + c) * 512 + ((chunk ^ swzA) << 3));
        const ushort* ybf = yf + ((size_t)(b * 256 + kcq * 16 + dh * 4)) * 512;
#pragma unroll
        for (int dt = 0; dt < 4; dt++) {
            f16x8 bfr = *(const f16x8*)(ybf + dt * 512 + L * 8);
            o[0][dt] = __builtin_amdgcn_mfma_f32_16x16x32_f16(af0, bfr, o[0][dt], 0, 0, 0);
            o[1][dt] = __builtin_amdgcn_mfma_f32_16x16x32_f16(af1, bfr, o[1][dt], 0, 0, 0);
        }
    }

    // ---- direct store (no exchange: each wave owns a d-quarter, full q summed) ----
#pragma unroll
    for (int rs = 0; rs < 2; rs++)
#pragma unroll
        for (int dt = 0; dt < 4; dt++)
#pragma unroll
            for (int r = 0; r < 4; r++) {
                int row = rs * 16 + quad * 4 + r;
                out[(size_t)(b * LP_ + m0 + row) * 256 + dh * 64 + dt * 16 + c] =
                    o[rs][dt][r];
            }
}

extern "C" void kernel_launch(void* const* d_in, const int* in_sizes, int n_in,
                              void* d_out, int out_size, void* d_ws, size_t ws_size,
                              hipStream_t stream) {
    const float* x    = (const float*)d_in[0];
    const float* y    = (const float*)d_in[1];
    const float* W    = (const float*)d_in[2];
    const float* bias = (const float*)d_in[3];
    float* out = (float*)d_out;

    char* ws = (char*)d_ws;
    size_t off = 0;
    ushort* Whf = (ushort*)(ws + off); off += (size_t)D_ * D_ * 2;          // 128KB
    ushort* yfb = (ushort*)(ws + off); off += (size_t)B_ * D_ * LQ_ * 2;    // 8MB
    ushort* ypf = (ushort*)(ws + off); off += (size_t)B_ * LQ_ * D_ * 2;    // 8MB
    ushort* xpf = (ushort*)(ws + off); off += (size_t)B_ * LP_ * D_ * 2;    // 32MB

    k_prep<<<768, 256, 0, stream>>>(W, y, Whf, yfb);
    k_proj<<<1280, 256, 0, stream>>>(x, y, Whf, bias, xpf, ypf);
    k_attn<<<B_ * 64, 256, 0, stream>>>(xpf, ypf, yfb, out);
}

// Round 5
// 202.976 us; speedup vs baseline: 1.0826x; 1.0069x over previous
//
#include <hip/hip_runtime.h>
#include <stdint.h>

// SeqAttnMatch: B=32, LP=2048, LQ=512, D=256, fp32 in/out. Single-plane fp16 pipeline.
// x-projection fused into k_attn (no xpf intermediate).
#define B_  32
#define LP_ 2048
#define LQ_ 512
#define D_  256

typedef __attribute__((ext_vector_type(8))) short short8;      // 8 x 16-bit
typedef __attribute__((ext_vector_type(8))) _Float16 f16x8;    // MFMA A/B frag (4 VGPRs)
typedef __attribute__((ext_vector_type(4))) float f32x4;

__device__ __forceinline__ ushort f2h(float x) {
    union { _Float16 h; ushort u; } v;
    v.h = (_Float16)x;                 // RNE convert
    return v.u;
}
// async global->LDS, 16B/lane; HW writes lds_base + lane*16 (wave-uniform base).
__device__ __forceinline__ void gl_lds16(const void* g, void* l) {
    __builtin_amdgcn_global_load_lds(
        (const __attribute__((address_space(1))) void*)g,
        (__attribute__((address_space(3))) void*)l, 16, 0, 0);
}

// Fragment-blocked layout: 1KB blocks of 512 ushorts. Element for lane
// L=quad*16+c, position L*8 + j, holds M[row_tile*16 + c][k0 + quad*8 + j].

// ---- K0: fused W f32->f16 frag convert (blocks 0..255) + y transpose (256..767) ----
// W block (kc=k/32, nt=e/16) at kc*16+nt. y block (b, qc=q/32, nt=d/16) at b*256+qc*16+nt,
// lane (c,quad,j) = y[qc*32+quad*8+j][nt*16+c] (Phase-C B operand: k=q, n=d).
__global__ void k_prep(const float* __restrict__ W, const float* __restrict__ y,
                       ushort* __restrict__ Whf, ushort* __restrict__ yf) {
    __shared__ float t[32 * 260];
    if (blockIdx.x < 256) {
        int i = blockIdx.x * 256 + threadIdx.x;
        int e = i >> 8, k = i & 255;
        size_t off = (size_t)((k >> 5) * 16 + (e >> 4)) * 512 +
                     ((k >> 3) & 3) * 128 + (e & 15) * 8 + (k & 7);
        Whf[off] = f2h(W[i]);
        return;
    }
    int bid = blockIdx.x - 256;      // 512 blocks
    int b = bid >> 4, qc = bid & 15;
    int tid = threadIdx.x;
    int ql = tid >> 3;               // 0..31
    int d0 = (tid & 7) * 4;
#pragma unroll
    for (int p = 0; p < 8; p++) {
        int d = p * 32 + d0;
        float4 v = *(const float4*)(y + ((size_t)(b * LQ_ + qc * 32 + ql) * 256 + d));
        t[ql * 260 + d + 0] = v.x; t[ql * 260 + d + 1] = v.y;
        t[ql * 260 + d + 2] = v.z; t[ql * 260 + d + 3] = v.w;
    }
    __syncthreads();
    int w = tid >> 6, L = tid & 63, c = L & 15, quad = L >> 4;
#pragma unroll
    for (int ii = 0; ii < 4; ii++) {
        int nt = w * 4 + ii;
        short8 o;
#pragma unroll
        for (int j = 0; j < 8; j++)
            o[j] = (short)f2h(t[(quad * 8 + j) * 260 + nt * 16 + c]);
        *(short8*)(yf + ((size_t)(b * 256 + qc * 16 + nt) * 512 + L * 8)) = o;
    }
}

// ---- K1: y-proj = relu(y @ W^T + b) -> frag-blocked f16 (256 blocks, 64 rows each) ----
// Output block layout: (rt_g>>5)*256 + ec*32 + (rt_g&31)  (Phase-A B-operand order).
__global__ __launch_bounds__(256, 3) void k_proj(const float* __restrict__ y,
                                                 const ushort* __restrict__ Whf,
                                                 const float* __restrict__ bias,
                                                 ushort* __restrict__ Oy) {
    __shared__ __align__(16) ushort Ws[16704];   // 32KB ping-pong, then 33.3KB transpose
    const int tid  = threadIdx.x;
    const int w    = tid >> 6;
    const int L    = tid & 63;
    const int c    = L & 15;
    const int quad = L >> 4;
    const int row0 = blockIdx.x * 64 + w * 16;
    const int arow = row0 + c;

    f32x4 acc[16];
#pragma unroll
    for (int i = 0; i < 16; i++) acc[i] = (f32x4)0.f;

#define PSTAGE(kc, p)                                                          \
    {                                                                          \
        _Pragma("unroll")                                                      \
        for (int ii = 0; ii < 4; ii++) {                                       \
            int i = w * 4 + ii;                                                \
            gl_lds16(Whf + (size_t)(kc) * 8192 + i * 512 + L * 8,              \
                     (char*)Ws + (p) * 16384 + i * 1024);                      \
        }                                                                      \
    }

    PSTAGE(0, 0);
    float4 nx0 = *(const float4*)(y + (size_t)arow * 256 + quad * 8);
    float4 nx1 = *(const float4*)(y + (size_t)arow * 256 + quad * 8 + 4);

    for (int kc = 0; kc < 8; kc++) {
        __syncthreads();
        if (kc < 7) PSTAGE(kc + 1, (kc + 1) & 1);
        float4 cx0 = nx0, cx1 = nx1;
        if (kc < 7) {
            nx0 = *(const float4*)(y + (size_t)arow * 256 + (kc + 1) * 32 + quad * 8);
            nx1 = *(const float4*)(y + (size_t)arow * 256 + (kc + 1) * 32 + quad * 8 + 4);
        }
        float xs[8] = {cx0.x, cx0.y, cx0.z, cx0.w, cx1.x, cx1.y, cx1.z, cx1.w};
        f16x8 ah;
#pragma unroll
        for (int j = 0; j < 8; j++) ah[j] = (_Float16)xs[j];
        const ushort* buf = Ws + (kc & 1) * 8192;
#pragma unroll
        for (int nt = 0; nt < 16; nt++) {
            f16x8 bh = *(const f16x8*)(buf + nt * 512 + L * 8);
            acc[nt] = __builtin_amdgcn_mfma_f32_16x16x32_f16(ah, bh, acc[nt], 0, 0, 0);
        }
    }

    // epilogue: bias+relu, per-wave LDS transpose C-layout -> B-frag layout
    __syncthreads();                 // all waves done reading Ws
    float* tr = (float*)Ws + w * (16 * 130);
    const int rt_g = row0 >> 4;
#pragma unroll
    for (int half = 0; half < 2; half++) {
#pragma unroll
        for (int nt8 = 0; nt8 < 8; nt8++) {
            int nt = half * 8 + nt8;
            float bv = bias[nt * 16 + c];
#pragma unroll
            for (int r = 0; r < 4; r++)
                tr[(quad * 4 + r) * 130 + nt8 * 16 + c] = fmaxf(acc[nt][r] + bv, 0.f);
        }
#pragma unroll
        for (int ec4 = 0; ec4 < 4; ec4++) {
            int ec = half * 4 + ec4;
            short8 hh;
#pragma unroll
            for (int j = 0; j < 8; j++)
                hh[j] = (short)f2h(tr[c * 130 + ec4 * 32 + quad * 8 + j]);
            size_t blk = (size_t)(rt_g >> 5) * 256 + ec * 32 + (rt_g & 31);
            *(short8*)(Oy + blk * 512 + L * 8) = hh;
        }
    }
}

// ---- K2: fused x-proj + scores + softmax + match. 32 rows/block, 2048 blocks. ----
// Front: stage x f32->f16 A-frags in LDS[0,16K); proj MFMA (wave=(rs,eh): 16 rows x
// 128 e) with B-frags from L2-resident Whf; relu+bias scatter f16 -> LDS[16K,32K)
// in Phase-A A-frag layout. Phases A/B/C unchanged from previous version.
__global__ __launch_bounds__(256, 4) void k_attn(const float* __restrict__ x,
                                                 const ushort* __restrict__ Whf,
                                                 const float* __restrict__ bias,
                                                 const ushort* __restrict__ ypf,
                                                 const ushort* __restrict__ yf,
                                                 float* __restrict__ out) {
    __shared__ __align__(16) ushort lds[16384];   // 32KB
    const int tid  = threadIdx.x;
    const int w    = tid >> 6;
    const int L    = tid & 63;
    const int c    = L & 15;
    const int quad = L >> 4;

    // XCD-affinity swizzle: XCD x sees only batches 4x..4x+3
    const int bid = blockIdx.x;
    const int jj  = bid >> 3;
    const int b   = (bid & 7) * 4 + (jj >> 6);
    const int mt  = jj & 63;                       // 0..63, 32 rows each
    const int m0  = mt * 32;

    // ---- stage x A-frags (inline f32->f16): 16 units (rs*8+kc) x 1KB ----
#pragma unroll
    for (int ii = 0; ii < 4; ii++) {
        int unit = w * 4 + ii;
        int rs = unit >> 3, kc = unit & 7;
        const float* xs = x + ((size_t)(b * LP_ + m0 + rs * 16 + c)) * 256 + kc * 32 + quad * 8;
        float4 v0 = *(const float4*)xs;
        float4 v1 = *(const float4*)(xs + 4);
        f16x8 h;
        h[0] = (_Float16)v0.x; h[1] = (_Float16)v0.y;
        h[2] = (_Float16)v0.z; h[3] = (_Float16)v0.w;
        h[4] = (_Float16)v1.x; h[5] = (_Float16)v1.y;
        h[6] = (_Float16)v1.z; h[7] = (_Float16)v1.w;
        *(f16x8*)(lds + unit * 512 + L * 8) = h;
    }
    __syncthreads();                 // x-frags visible

    // ---- x-proj: wave (prs=w&1, peh=w>>1): rows prs*16..+16, e peh*128..+128 ----
    {
        const int prs = w & 1, peh = w >> 1;
        float bv[8];
#pragma unroll
        for (int ne = 0; ne < 8; ne++) bv[ne] = bias[(peh * 8 + ne) * 16 + c];
        f32x4 pacc[8];
#pragma unroll
        for (int ne = 0; ne < 8; ne++) pacc[ne] = (f32x4)0.f;
        for (int kc = 0; kc < 8; kc++) {
            f16x8 ah = *(const f16x8*)(lds + (prs * 8 + kc) * 512 + L * 8);
#pragma unroll
            for (int ne = 0; ne < 8; ne++) {
                f16x8 wb = *(const f16x8*)(Whf + ((size_t)(kc * 16 + peh * 8 + ne)) * 512 + L * 8);
                pacc[ne] = __builtin_amdgcn_mfma_f32_16x16x32_f16(ah, wb, pacc[ne], 0, 0, 0);
            }
        }
        // scatter relu(acc+bias) f16 -> pfrag LDS [16K,32K) in A-frag layout.
        // e = peh*128+ne*16+c; row-in-tile c' = quad*4+r; unit = prs*8 + (e>>5).
#pragma unroll
        for (int ne = 0; ne < 8; ne++) {
#pragma unroll
            for (int r = 0; r < 4; r++) {
                float v = fmaxf(pacc[ne][r] + bv[ne], 0.f);
                int off = 8192 + (prs * 8 + peh * 4 + (ne >> 1)) * 512 +
                          ((ne & 1) * 2 + (c >> 3)) * 128 + (quad * 4 + r) * 8 + (c & 7);
                lds[off] = f2h(v);
            }
        }
    }

    f32x4 sc[2][8];
#pragma unroll
    for (int rs = 0; rs < 2; rs++)
#pragma unroll
        for (int qt = 0; qt < 8; qt++) sc[rs][qt] = (f32x4)0.f;
    __syncthreads();                 // proj frags visible

    // ---- Phase A: barrier-free; B-frags coalesced from L2-resident ypf ----
    const ushort* pf = lds + 8192;   // proj A-frags
    const ushort* yb = ypf + (size_t)b * 256 * 512;
    for (int kc = 0; kc < 8; kc++) {
        f16x8 ah0 = *(const f16x8*)(pf + kc * 512 + L * 8);
        f16x8 ah1 = *(const f16x8*)(pf + (8 + kc) * 512 + L * 8);
#pragma unroll
        for (int qt = 0; qt < 8; qt++) {
            f16x8 bh = *(const f16x8*)(yb + ((size_t)kc * 32 + w * 8 + qt) * 512 + L * 8);
            sc[0][qt] = __builtin_amdgcn_mfma_f32_16x16x32_f16(ah0, bh, sc[0][qt], 0, 0, 0);
            sc[1][qt] = __builtin_amdgcn_mfma_f32_16x16x32_f16(ah1, bh, sc[1][qt], 0, 0, 0);
        }
    }

    // ---- Phase B: softmax; each wave holds a q-quarter of every row ----
    __syncthreads();                 // proj-frag reads done; lds reusable
    float* red  = (float*)lds;       // [32][4] partial max (x-frag region, dead)
    float* red2 = red + 128;         // [32][4] partial sum
    float inv[2][4];
#pragma unroll
    for (int rs = 0; rs < 2; rs++)
#pragma unroll
        for (int r = 0; r < 4; r++) {
            float pm = sc[rs][0][r];
#pragma unroll
            for (int qt = 1; qt < 8; qt++) pm = fmaxf(pm, sc[rs][qt][r]);
#pragma unroll
            for (int mask = 1; mask <= 8; mask <<= 1) pm = fmaxf(pm, __shfl_xor(pm, mask));
            if (c == 0) red[(rs * 16 + quad * 4 + r) * 4 + w] = pm;
        }
    __syncthreads();
#pragma unroll
    for (int rs = 0; rs < 2; rs++)
#pragma unroll
        for (int r = 0; r < 4; r++) {
            int row = rs * 16 + quad * 4 + r;
            float m = fmaxf(fmaxf(red[row * 4], red[row * 4 + 1]),
                            fmaxf(red[row * 4 + 2], red[row * 4 + 3]));
            float ps = 0.f;
#pragma unroll
            for (int qt = 0; qt < 8; qt++) {
                float e = __expf(sc[rs][qt][r] - m);
                sc[rs][qt][r] = e;
                ps += e;
            }
#pragma unroll
            for (int mask = 1; mask <= 8; mask <<= 1) ps += __shfl_xor(ps, mask);
            if (c == 0) red2[row * 4 + w] = ps;
        }
    __syncthreads();
#pragma unroll
    for (int rs = 0; rs < 2; rs++)
#pragma unroll
        for (int r = 0; r < 4; r++) {
            int row = rs * 16 + quad * 4 + r;
            inv[rs][r] = 1.f / (red2[row * 4] + red2[row * 4 + 1] +
                                red2[row * 4 + 2] + red2[row * 4 + 3]);
        }
    __syncthreads();                 // red/red2 reads done before alpha overwrites

    // alpha (f16) -> LDS [32 rows][512 q], xor-swizzled 8-elem chunks
#pragma unroll
    for (int rs = 0; rs < 2; rs++)
#pragma unroll
        for (int r = 0; r < 4; r++) {
            int m_loc = rs * 16 + quad * 4 + r;
            int swz = m_loc & 7;
            float iv = inv[rs][r];
#pragma unroll
            for (int qt = 0; qt < 8; qt++) {
                int q = w * 128 + qt * 16 + c;
                lds[m_loc * 512 + (((q >> 3) ^ swz) << 3) + (c & 7)] = f2h(sc[rs][qt][r] * iv);
            }
        }
    __syncthreads();

    // ---- Phase C: out = alpha(LDS) @ yf(global). wave w = d-quarter, full q sweep. ----
    f32x4 o[2][4];
#pragma unroll
    for (int rs = 0; rs < 2; rs++)
#pragma unroll
        for (int dt = 0; dt < 4; dt++) o[rs][dt] = (f32x4)0.f;
    const int dh = w;
    const int swzA = c & 7;          // (rs*16+c)&7 == c&7
    for (int kcq = 0; kcq < 16; kcq++) {
        int chunk = kcq * 4 + quad;
        f16x8 af0 = *(const f16x8*)(lds + c * 512 + ((chunk ^ swzA) << 3));
        f16x8 af1 = *(const f16x8*)(lds + (16 + c) * 512 + ((chunk ^ swzA) << 3));
        const ushort* ybf = yf + ((size_t)(b * 256 + kcq * 16 + dh * 4)) * 512;
#pragma unroll
        for (int dt = 0; dt < 4; dt++) {
            f16x8 bfr = *(const f16x8*)(ybf + dt * 512 + L * 8);
            o[0][dt] = __builtin_amdgcn_mfma_f32_16x16x32_f16(af0, bfr, o[0][dt], 0, 0, 0);
            o[1][dt] = __builtin_amdgcn_mfma_f32_16x16x32_f16(af1, bfr, o[1][dt], 0, 0, 0);
        }
    }

    // ---- direct store (no exchange: each wave owns a d-quarter, full q summed) ----
#pragma unroll
    for (int rs = 0; rs < 2; rs++)
#pragma unroll
        for (int dt = 0; dt < 4; dt++)
#pragma unroll
            for (int r = 0; r < 4; r++) {
                int row = rs * 16 + quad * 4 + r;
                out[(size_t)(b * LP_ + m0 + row) * 256 + dh * 64 + dt * 16 + c] =
                    o[rs][dt][r];
            }
}

extern "C" void kernel_launch(void* const* d_in, const int* in_sizes, int n_in,
                              void* d_out, int out_size, void* d_ws, size_t ws_size,
                              hipStream_t stream) {
    const float* x    = (const float*)d_in[0];
    const float* y    = (const float*)d_in[1];
    const float* W    = (const float*)d_in[2];
    const float* bias = (const float*)d_in[3];
    float* out = (float*)d_out;

    char* ws = (char*)d_ws;
    size_t off = 0;
    ushort* Whf = (ushort*)(ws + off); off += (size_t)D_ * D_ * 2;          // 128KB
    ushort* yfb = (ushort*)(ws + off); off += (size_t)B_ * D_ * LQ_ * 2;    // 8MB
    ushort* ypf = (ushort*)(ws + off); off += (size_t)B_ * LQ_ * D_ * 2;    // 8MB

    k_prep<<<768, 256, 0, stream>>>(W, y, Whf, yfb);
    k_proj<<<256, 256, 0, stream>>>(y, Whf, bias, ypf);
    k_attn<<<B_ * 64, 256, 0, stream>>>(x, Whf, bias, ypf, yfb, out);
}

// Round 6
// 196.432 us; speedup vs baseline: 1.1186x; 1.0333x over previous
//
#include <hip/hip_runtime.h>
#include <stdint.h>

// SeqAttnMatch: B=32, LP=2048, LQ=512, D=256, fp32 in/out. Single-plane fp16 pipeline.
// x-projection fused into k_attn (no xpf intermediate).
#define B_  32
#define LP_ 2048
#define LQ_ 512
#define D_  256

typedef __attribute__((ext_vector_type(8))) short short8;      // 8 x 16-bit
typedef __attribute__((ext_vector_type(8))) _Float16 f16x8;    // MFMA A/B frag (4 VGPRs)
typedef __attribute__((ext_vector_type(4))) float f32x4;

__device__ __forceinline__ ushort f2h(float x) {
    union { _Float16 h; ushort u; } v;
    v.h = (_Float16)x;                 // RNE convert
    return v.u;
}
// async global->LDS, 16B/lane; HW writes lds_base + lane*16 (wave-uniform base).
__device__ __forceinline__ void gl_lds16(const void* g, void* l) {
    __builtin_amdgcn_global_load_lds(
        (const __attribute__((address_space(1))) void*)g,
        (__attribute__((address_space(3))) void*)l, 16, 0, 0);
}

// Fragment-blocked layout: 1KB blocks of 512 ushorts. Element for lane
// L=quad*16+c, position L*8 + j, holds M[row_tile*16 + c][k0 + quad*8 + j].

// ---- K0: fused W f32->f16 frag convert (blocks 0..255) + y transpose (256..767) ----
// W block (kc=k/32, nt=e/16) at kc*16+nt. y block (b, qc=q/32, nt=d/16) at b*256+qc*16+nt,
// lane (c,quad,j) = y[qc*32+quad*8+j][nt*16+c] (Phase-C B operand: k=q, n=d).
__global__ void k_prep(const float* __restrict__ W, const float* __restrict__ y,
                       ushort* __restrict__ Whf, ushort* __restrict__ yf) {
    __shared__ float t[32 * 260];
    if (blockIdx.x < 256) {
        int i = blockIdx.x * 256 + threadIdx.x;
        int e = i >> 8, k = i & 255;
        size_t off = (size_t)((k >> 5) * 16 + (e >> 4)) * 512 +
                     ((k >> 3) & 3) * 128 + (e & 15) * 8 + (k & 7);
        Whf[off] = f2h(W[i]);
        return;
    }
    int bid = blockIdx.x - 256;      // 512 blocks
    int b = bid >> 4, qc = bid & 15;
    int tid = threadIdx.x;
    int ql = tid >> 3;               // 0..31
    int d0 = (tid & 7) * 4;
#pragma unroll
    for (int p = 0; p < 8; p++) {
        int d = p * 32 + d0;
        float4 v = *(const float4*)(y + ((size_t)(b * LQ_ + qc * 32 + ql) * 256 + d));
        t[ql * 260 + d + 0] = v.x; t[ql * 260 + d + 1] = v.y;
        t[ql * 260 + d + 2] = v.z; t[ql * 260 + d + 3] = v.w;
    }
    __syncthreads();
    int w = tid >> 6, L = tid & 63, c = L & 15, quad = L >> 4;
#pragma unroll
    for (int ii = 0; ii < 4; ii++) {
        int nt = w * 4 + ii;
        short8 o;
#pragma unroll
        for (int j = 0; j < 8; j++)
            o[j] = (short)f2h(t[(quad * 8 + j) * 260 + nt * 16 + c]);
        *(short8*)(yf + ((size_t)(b * 256 + qc * 16 + nt) * 512 + L * 8)) = o;
    }
}

// ---- K1: y-proj = relu(y @ W^T + b) -> frag-blocked f16 (256 blocks, 64 rows each) ----
// Output block layout: (rt_g>>5)*256 + ec*32 + (rt_g&31)  (Phase-A B-operand order).
__global__ __launch_bounds__(256, 3) void k_proj(const float* __restrict__ y,
                                                 const ushort* __restrict__ Whf,
                                                 const float* __restrict__ bias,
                                                 ushort* __restrict__ Oy) {
    __shared__ __align__(16) ushort Ws[16704];   // 32KB ping-pong, then 33.3KB transpose
    const int tid  = threadIdx.x;
    const int w    = tid >> 6;
    const int L    = tid & 63;
    const int c    = L & 15;
    const int quad = L >> 4;
    const int row0 = blockIdx.x * 64 + w * 16;
    const int arow = row0 + c;

    f32x4 acc[16];
#pragma unroll
    for (int i = 0; i < 16; i++) acc[i] = (f32x4)0.f;

#define PSTAGE(kc, p)                                                          \
    {                                                                          \
        _Pragma("unroll")                                                      \
        for (int ii = 0; ii < 4; ii++) {                                       \
            int i = w * 4 + ii;                                                \
            gl_lds16(Whf + (size_t)(kc) * 8192 + i * 512 + L * 8,              \
                     (char*)Ws + (p) * 16384 + i * 1024);                      \
        }                                                                      \
    }

    PSTAGE(0, 0);
    float4 nx0 = *(const float4*)(y + (size_t)arow * 256 + quad * 8);
    float4 nx1 = *(const float4*)(y + (size_t)arow * 256 + quad * 8 + 4);

    for (int kc = 0; kc < 8; kc++) {
        __syncthreads();
        if (kc < 7) PSTAGE(kc + 1, (kc + 1) & 1);
        float4 cx0 = nx0, cx1 = nx1;
        if (kc < 7) {
            nx0 = *(const float4*)(y + (size_t)arow * 256 + (kc + 1) * 32 + quad * 8);
            nx1 = *(const float4*)(y + (size_t)arow * 256 + (kc + 1) * 32 + quad * 8 + 4);
        }
        float xs[8] = {cx0.x, cx0.y, cx0.z, cx0.w, cx1.x, cx1.y, cx1.z, cx1.w};
        f16x8 ah;
#pragma unroll
        for (int j = 0; j < 8; j++) ah[j] = (_Float16)xs[j];
        const ushort* buf = Ws + (kc & 1) * 8192;
#pragma unroll
        for (int nt = 0; nt < 16; nt++) {
            f16x8 bh = *(const f16x8*)(buf + nt * 512 + L * 8);
            acc[nt] = __builtin_amdgcn_mfma_f32_16x16x32_f16(ah, bh, acc[nt], 0, 0, 0);
        }
    }

    // epilogue: bias+relu, per-wave LDS transpose C-layout -> B-frag layout
    __syncthreads();                 // all waves done reading Ws
    float* tr = (float*)Ws + w * (16 * 130);
    const int rt_g = row0 >> 4;
#pragma unroll
    for (int half = 0; half < 2; half++) {
#pragma unroll
        for (int nt8 = 0; nt8 < 8; nt8++) {
            int nt = half * 8 + nt8;
            float bv = bias[nt * 16 + c];
#pragma unroll
            for (int r = 0; r < 4; r++)
                tr[(quad * 4 + r) * 130 + nt8 * 16 + c] = fmaxf(acc[nt][r] + bv, 0.f);
        }
#pragma unroll
        for (int ec4 = 0; ec4 < 4; ec4++) {
            int ec = half * 4 + ec4;
            short8 hh;
#pragma unroll
            for (int j = 0; j < 8; j++)
                hh[j] = (short)f2h(tr[c * 130 + ec4 * 32 + quad * 8 + j]);
            size_t blk = (size_t)(rt_g >> 5) * 256 + ec * 32 + (rt_g & 31);
            *(short8*)(Oy + blk * 512 + L * 8) = hh;
        }
    }
}

// ---- K2: fused x-proj + scores + softmax + match. 32 rows/block, 2048 blocks. ----
// Front: stage x f32->f16 A-frags in LDS[0,16K); proj MFMA wave=(e-quarter w, BOTH
// row-tiles): per wave 4 Whf frags/kc (no intra-block Whf redundancy, 128KB/block);
// relu+bias scatter f16 -> LDS[16K,32K) in Phase-A A-frag layout.
// Phases A/B/C unchanged.
__global__ __launch_bounds__(256, 4) void k_attn(const float* __restrict__ x,
                                                 const ushort* __restrict__ Whf,
                                                 const float* __restrict__ bias,
                                                 const ushort* __restrict__ ypf,
                                                 const ushort* __restrict__ yf,
                                                 float* __restrict__ out) {
    __shared__ __align__(16) ushort lds[16384];   // 32KB
    const int tid  = threadIdx.x;
    const int w    = tid >> 6;
    const int L    = tid & 63;
    const int c    = L & 15;
    const int quad = L >> 4;

    // XCD-affinity swizzle: XCD x sees only batches 4x..4x+3
    const int bid = blockIdx.x;
    const int jj  = bid >> 3;
    const int b   = (bid & 7) * 4 + (jj >> 6);
    const int mt  = jj & 63;                       // 0..63, 32 rows each
    const int m0  = mt * 32;

    // ---- stage x A-frags (inline f32->f16): 16 units (rs*8+kc) x 1KB ----
#pragma unroll
    for (int ii = 0; ii < 4; ii++) {
        int unit = w * 4 + ii;
        int rs = unit >> 3, kc = unit & 7;
        const float* xs = x + ((size_t)(b * LP_ + m0 + rs * 16 + c)) * 256 + kc * 32 + quad * 8;
        float4 v0 = *(const float4*)xs;
        float4 v1 = *(const float4*)(xs + 4);
        f16x8 h;
        h[0] = (_Float16)v0.x; h[1] = (_Float16)v0.y;
        h[2] = (_Float16)v0.z; h[3] = (_Float16)v0.w;
        h[4] = (_Float16)v1.x; h[5] = (_Float16)v1.y;
        h[6] = (_Float16)v1.z; h[7] = (_Float16)v1.w;
        *(f16x8*)(lds + unit * 512 + L * 8) = h;
    }
    __syncthreads();                 // x-frags visible

    // ---- x-proj: wave w = e-quarter (4 nt), BOTH row-tiles rs=0,1 ----
    {
        float bv[4];
#pragma unroll
        for (int ne = 0; ne < 4; ne++) bv[ne] = bias[(w * 4 + ne) * 16 + c];
        f32x4 pacc[2][4];
#pragma unroll
        for (int rs = 0; rs < 2; rs++)
#pragma unroll
            for (int ne = 0; ne < 4; ne++) pacc[rs][ne] = (f32x4)0.f;
        for (int kc = 0; kc < 8; kc++) {
            f16x8 ah0 = *(const f16x8*)(lds + kc * 512 + L * 8);
            f16x8 ah1 = *(const f16x8*)(lds + (8 + kc) * 512 + L * 8);
#pragma unroll
            for (int ne = 0; ne < 4; ne++) {
                f16x8 wb = *(const f16x8*)(Whf + ((size_t)(kc * 16 + w * 4 + ne)) * 512 + L * 8);
                pacc[0][ne] = __builtin_amdgcn_mfma_f32_16x16x32_f16(ah0, wb, pacc[0][ne], 0, 0, 0);
                pacc[1][ne] = __builtin_amdgcn_mfma_f32_16x16x32_f16(ah1, wb, pacc[1][ne], 0, 0, 0);
            }
        }
        // scatter relu(acc+bias) f16 -> pfrag LDS [16K,32K) in A-frag layout.
        // e = (w*4+ne)*16+c; row = rs*16+quad*4+r; unit = rs*8 + (e>>5) = rs*8+w*2+(ne>>1).
#pragma unroll
        for (int rs = 0; rs < 2; rs++)
#pragma unroll
            for (int ne = 0; ne < 4; ne++) {
#pragma unroll
                for (int r = 0; r < 4; r++) {
                    float v = fmaxf(pacc[rs][ne][r] + bv[ne], 0.f);
                    int off = 8192 + (rs * 8 + w * 2 + (ne >> 1)) * 512 +
                              ((ne & 1) * 2 + (c >> 3)) * 128 + (quad * 4 + r) * 8 + (c & 7);
                    lds[off] = f2h(v);
                }
            }
    }

    f32x4 sc[2][8];
#pragma unroll
    for (int rs = 0; rs < 2; rs++)
#pragma unroll
        for (int qt = 0; qt < 8; qt++) sc[rs][qt] = (f32x4)0.f;
    __syncthreads();                 // proj frags visible

    // ---- Phase A: barrier-free; B-frags coalesced from L2-resident ypf ----
    const ushort* pf = lds + 8192;   // proj A-frags
    const ushort* yb = ypf + (size_t)b * 256 * 512;
    for (int kc = 0; kc < 8; kc++) {
        f16x8 ah0 = *(const f16x8*)(pf + kc * 512 + L * 8);
        f16x8 ah1 = *(const f16x8*)(pf + (8 + kc) * 512 + L * 8);
#pragma unroll
        for (int qt = 0; qt < 8; qt++) {
            f16x8 bh = *(const f16x8*)(yb + ((size_t)kc * 32 + w * 8 + qt) * 512 + L * 8);
            sc[0][qt] = __builtin_amdgcn_mfma_f32_16x16x32_f16(ah0, bh, sc[0][qt], 0, 0, 0);
            sc[1][qt] = __builtin_amdgcn_mfma_f32_16x16x32_f16(ah1, bh, sc[1][qt], 0, 0, 0);
        }
    }

    // ---- Phase B: softmax; each wave holds a q-quarter of every row ----
    __syncthreads();                 // proj-frag reads done; lds reusable
    float* red  = (float*)lds;       // [32][4] partial max (x-frag region, dead)
    float* red2 = red + 128;         // [32][4] partial sum
    float inv[2][4];
#pragma unroll
    for (int rs = 0; rs < 2; rs++)
#pragma unroll
        for (int r = 0; r < 4; r++) {
            float pm = sc[rs][0][r];
#pragma unroll
            for (int qt = 1; qt < 8; qt++) pm = fmaxf(pm, sc[rs][qt][r]);
#pragma unroll
            for (int mask = 1; mask <= 8; mask <<= 1) pm = fmaxf(pm, __shfl_xor(pm, mask));
            if (c == 0) red[(rs * 16 + quad * 4 + r) * 4 + w] = pm;
        }
    __syncthreads();
#pragma unroll
    for (int rs = 0; rs < 2; rs++)
#pragma unroll
        for (int r = 0; r < 4; r++) {
            int row = rs * 16 + quad * 4 + r;
            float m = fmaxf(fmaxf(red[row * 4], red[row * 4 + 1]),
                            fmaxf(red[row * 4 + 2], red[row * 4 + 3]));
            float ps = 0.f;
#pragma unroll
            for (int qt = 0; qt < 8; qt++) {
                float e = __expf(sc[rs][qt][r] - m);
                sc[rs][qt][r] = e;
                ps += e;
            }
#pragma unroll
            for (int mask = 1; mask <= 8; mask <<= 1) ps += __shfl_xor(ps, mask);
            if (c == 0) red2[row * 4 + w] = ps;
        }
    __syncthreads();
#pragma unroll
    for (int rs = 0; rs < 2; rs++)
#pragma unroll
        for (int r = 0; r < 4; r++) {
            int row = rs * 16 + quad * 4 + r;
            inv[rs][r] = 1.f / (red2[row * 4] + red2[row * 4 + 1] +
                                red2[row * 4 + 2] + red2[row * 4 + 3]);
        }
    __syncthreads();                 // red/red2 reads done before alpha overwrites

    // alpha (f16) -> LDS [32 rows][512 q], xor-swizzled 8-elem chunks
#pragma unroll
    for (int rs = 0; rs < 2; rs++)
#pragma unroll
        for (int r = 0; r < 4; r++) {
            int m_loc = rs * 16 + quad * 4 + r;
            int swz = m_loc & 7;
            float iv = inv[rs][r];
#pragma unroll
            for (int qt = 0; qt < 8; qt++) {
                int q = w * 128 + qt * 16 + c;
                lds[m_loc * 512 + (((q >> 3) ^ swz) << 3) + (c & 7)] = f2h(sc[rs][qt][r] * iv);
            }
        }
    __syncthreads();

    // ---- Phase C: out = alpha(LDS) @ yf(global). wave w = d-quarter, full q sweep. ----
    f32x4 o[2][4];
#pragma unroll
    for (int rs = 0; rs < 2; rs++)
#pragma unroll
        for (int dt = 0; dt < 4; dt++) o[rs][dt] = (f32x4)0.f;
    const int dh = w;
    const int swzA = c & 7;          // (rs*16+c)&7 == c&7
    for (int kcq = 0; kcq < 16; kcq++) {
        int chunk = kcq * 4 + quad;
        f16x8 af0 = *(const f16x8*)(lds + c * 512 + ((chunk ^ swzA) << 3));
        f16x8 af1 = *(const f16x8*)(lds + (16 + c) * 512 + ((chunk ^ swzA) << 3));
        const ushort* ybf = yf + ((size_t)(b * 256 + kcq * 16 + dh * 4)) * 512;
#pragma unroll
        for (int dt = 0; dt < 4; dt++) {
            f16x8 bfr = *(const f16x8*)(ybf + dt * 512 + L * 8);
            o[0][dt] = __builtin_amdgcn_mfma_f32_16x16x32_f16(af0, bfr, o[0][dt], 0, 0, 0);
            o[1][dt] = __builtin_amdgcn_mfma_f32_16x16x32_f16(af1, bfr, o[1][dt], 0, 0, 0);
        }
    }

    // ---- direct store (no exchange: each wave owns a d-quarter, full q summed) ----
#pragma unroll
    for (int rs = 0; rs < 2; rs++)
#pragma unroll
        for (int dt = 0; dt < 4; dt++)
#pragma unroll
            for (int r = 0; r < 4; r++) {
                int row = rs * 16 + quad * 4 + r;
                out[(size_t)(b * LP_ + m0 + row) * 256 + dh * 64 + dt * 16 + c] =
                    o[rs][dt][r];
            }
}

extern "C" void kernel_launch(void* const* d_in, const int* in_sizes, int n_in,
                              void* d_out, int out_size, void* d_ws, size_t ws_size,
                              hipStream_t stream) {
    const float* x    = (const float*)d_in[0];
    const float* y    = (const float*)d_in[1];
    const float* W    = (const float*)d_in[2];
    const float* bias = (const float*)d_in[3];
    float* out = (float*)d_out;

    char* ws = (char*)d_ws;
    size_t off = 0;
    ushort* Whf = (ushort*)(ws + off); off += (size_t)D_ * D_ * 2;          // 128KB
    ushort* yfb = (ushort*)(ws + off); off += (size_t)B_ * D_ * LQ_ * 2;    // 8MB
    ushort* ypf = (ushort*)(ws + off); off += (size_t)B_ * LQ_ * D_ * 2;    // 8MB

    k_prep<<<768, 256, 0, stream>>>(W, y, Whf, yfb);
    k_proj<<<256, 256, 0, stream>>>(y, Whf, bias, ypf);
    k_attn<<<B_ * 64, 256, 0, stream>>>(x, Whf, bias, ypf, yfb, out);
}

// Round 7
// 194.801 us; speedup vs baseline: 1.1280x; 1.0084x over previous
//
#include <hip/hip_runtime.h>
#include <stdint.h>

// SeqAttnMatch: B=32, LP=2048, LQ=512, D=256, fp32 in/out. Single-plane fp16 pipeline.
// x-projection fused into k_attn; sched_barrier-fenced 1-deep register pipelines.
#define B_  32
#define LP_ 2048
#define LQ_ 512
#define D_  256

typedef __attribute__((ext_vector_type(8))) short short8;      // 8 x 16-bit
typedef __attribute__((ext_vector_type(8))) _Float16 f16x8;    // MFMA A/B frag (4 VGPRs)
typedef __attribute__((ext_vector_type(4))) float f32x4;

__device__ __forceinline__ ushort f2h(float x) {
    union { _Float16 h; ushort u; } v;
    v.h = (_Float16)x;                 // RNE convert
    return v.u;
}
// async global->LDS, 16B/lane; HW writes lds_base + lane*16 (wave-uniform base).
__device__ __forceinline__ void gl_lds16(const void* g, void* l) {
    __builtin_amdgcn_global_load_lds(
        (const __attribute__((address_space(1))) void*)g,
        (__attribute__((address_space(3))) void*)l, 16, 0, 0);
}

// Fragment-blocked layout: 1KB blocks of 512 ushorts. Element for lane
// L=quad*16+c, position L*8 + j, holds M[row_tile*16 + c][k0 + quad*8 + j].

// ---- K0: fused W f32->f16 frag convert (blocks 0..255) + y transpose (256..767) ----
__global__ void k_prep(const float* __restrict__ W, const float* __restrict__ y,
                       ushort* __restrict__ Whf, ushort* __restrict__ yf) {
    __shared__ float t[32 * 260];
    if (blockIdx.x < 256) {
        int i = blockIdx.x * 256 + threadIdx.x;
        int e = i >> 8, k = i & 255;
        size_t off = (size_t)((k >> 5) * 16 + (e >> 4)) * 512 +
                     ((k >> 3) & 3) * 128 + (e & 15) * 8 + (k & 7);
        Whf[off] = f2h(W[i]);
        return;
    }
    int bid = blockIdx.x - 256;      // 512 blocks
    int b = bid >> 4, qc = bid & 15;
    int tid = threadIdx.x;
    int ql = tid >> 3;               // 0..31
    int d0 = (tid & 7) * 4;
#pragma unroll
    for (int p = 0; p < 8; p++) {
        int d = p * 32 + d0;
        float4 v = *(const float4*)(y + ((size_t)(b * LQ_ + qc * 32 + ql) * 256 + d));
        t[ql * 260 + d + 0] = v.x; t[ql * 260 + d + 1] = v.y;
        t[ql * 260 + d + 2] = v.z; t[ql * 260 + d + 3] = v.w;
    }
    __syncthreads();
    int w = tid >> 6, L = tid & 63, c = L & 15, quad = L >> 4;
#pragma unroll
    for (int ii = 0; ii < 4; ii++) {
        int nt = w * 4 + ii;
        short8 o;
#pragma unroll
        for (int j = 0; j < 8; j++)
            o[j] = (short)f2h(t[(quad * 8 + j) * 260 + nt * 16 + c]);
        *(short8*)(yf + ((size_t)(b * 256 + qc * 16 + nt) * 512 + L * 8)) = o;
    }
}

// ---- K1: y-proj = relu(y @ W^T + b) -> frag-blocked f16 (256 blocks, 64 rows each) ----
__global__ __launch_bounds__(256, 3) void k_proj(const float* __restrict__ y,
                                                 const ushort* __restrict__ Whf,
                                                 const float* __restrict__ bias,
                                                 ushort* __restrict__ Oy) {
    __shared__ __align__(16) ushort Ws[16704];   // 32KB ping-pong, then 33.3KB transpose
    const int tid  = threadIdx.x;
    const int w    = tid >> 6;
    const int L    = tid & 63;
    const int c    = L & 15;
    const int quad = L >> 4;
    const int row0 = blockIdx.x * 64 + w * 16;
    const int arow = row0 + c;

    f32x4 acc[16];
#pragma unroll
    for (int i = 0; i < 16; i++) acc[i] = (f32x4)0.f;

#define PSTAGE(kc, p)                                                          \
    {                                                                          \
        _Pragma("unroll")                                                      \
        for (int ii = 0; ii < 4; ii++) {                                       \
            int i = w * 4 + ii;                                                \
            gl_lds16(Whf + (size_t)(kc) * 8192 + i * 512 + L * 8,              \
                     (char*)Ws + (p) * 16384 + i * 1024);                      \
        }                                                                      \
    }

    PSTAGE(0, 0);
    float4 nx0 = *(const float4*)(y + (size_t)arow * 256 + quad * 8);
    float4 nx1 = *(const float4*)(y + (size_t)arow * 256 + quad * 8 + 4);

    for (int kc = 0; kc < 8; kc++) {
        __syncthreads();
        if (kc < 7) PSTAGE(kc + 1, (kc + 1) & 1);
        float4 cx0 = nx0, cx1 = nx1;
        if (kc < 7) {
            nx0 = *(const float4*)(y + (size_t)arow * 256 + (kc + 1) * 32 + quad * 8);
            nx1 = *(const float4*)(y + (size_t)arow * 256 + (kc + 1) * 32 + quad * 8 + 4);
        }
        float xs[8] = {cx0.x, cx0.y, cx0.z, cx0.w, cx1.x, cx1.y, cx1.z, cx1.w};
        f16x8 ah;
#pragma unroll
        for (int j = 0; j < 8; j++) ah[j] = (_Float16)xs[j];
        const ushort* buf = Ws + (kc & 1) * 8192;
#pragma unroll
        for (int nt = 0; nt < 16; nt++) {
            f16x8 bh = *(const f16x8*)(buf + nt * 512 + L * 8);
            acc[nt] = __builtin_amdgcn_mfma_f32_16x16x32_f16(ah, bh, acc[nt], 0, 0, 0);
        }
    }

    // epilogue: bias+relu, per-wave LDS transpose C-layout -> B-frag layout
    __syncthreads();                 // all waves done reading Ws
    float* tr = (float*)Ws + w * (16 * 130);
    const int rt_g = row0 >> 4;
#pragma unroll
    for (int half = 0; half < 2; half++) {
#pragma unroll
        for (int nt8 = 0; nt8 < 8; nt8++) {
            int nt = half * 8 + nt8;
            float bv = bias[nt * 16 + c];
#pragma unroll
            for (int r = 0; r < 4; r++)
                tr[(quad * 4 + r) * 130 + nt8 * 16 + c] = fmaxf(acc[nt][r] + bv, 0.f);
        }
#pragma unroll
        for (int ec4 = 0; ec4 < 4; ec4++) {
            int ec = half * 4 + ec4;
            short8 hh;
#pragma unroll
            for (int j = 0; j < 8; j++)
                hh[j] = (short)f2h(tr[c * 130 + ec4 * 32 + quad * 8 + j]);
            size_t blk = (size_t)(rt_g >> 5) * 256 + ec * 32 + (rt_g & 31);
            *(short8*)(Oy + blk * 512 + L * 8) = hh;
        }
    }
}

// ---- K2: fused x-proj + scores + softmax + match. 32 rows/block, 2048 blocks. ----
// 3 blocks/CU (170 regs/wave) buys register headroom for 1-deep load pipelines in
// proj / Phase A / Phase C, fenced with sched_barrier(0) so hipcc can't sink them.
__global__ __launch_bounds__(256, 3) void k_attn(const float* __restrict__ x,
                                                 const ushort* __restrict__ Whf,
                                                 const float* __restrict__ bias,
                                                 const ushort* __restrict__ ypf,
                                                 const ushort* __restrict__ yf,
                                                 float* __restrict__ out) {
    __shared__ __align__(16) ushort lds[16384];   // 32KB
    const int tid  = threadIdx.x;
    const int w    = tid >> 6;
    const int L    = tid & 63;
    const int c    = L & 15;
    const int quad = L >> 4;

    // XCD-affinity swizzle: XCD x sees only batches 4x..4x+3
    const int bid = blockIdx.x;
    const int jj  = bid >> 3;
    const int b   = (bid & 7) * 4 + (jj >> 6);
    const int mt  = jj & 63;                       // 0..63, 32 rows each
    const int m0  = mt * 32;

    // ---- stage x A-frags (inline f32->f16): 16 units (rs*8+kc) x 1KB ----
#pragma unroll
    for (int ii = 0; ii < 4; ii++) {
        int unit = w * 4 + ii;
        int rs = unit >> 3, kc = unit & 7;
        const float* xs = x + ((size_t)(b * LP_ + m0 + rs * 16 + c)) * 256 + kc * 32 + quad * 8;
        float4 v0 = *(const float4*)xs;
        float4 v1 = *(const float4*)(xs + 4);
        f16x8 h;
        h[0] = (_Float16)v0.x; h[1] = (_Float16)v0.y;
        h[2] = (_Float16)v0.z; h[3] = (_Float16)v0.w;
        h[4] = (_Float16)v1.x; h[5] = (_Float16)v1.y;
        h[6] = (_Float16)v1.z; h[7] = (_Float16)v1.w;
        *(f16x8*)(lds + unit * 512 + L * 8) = h;
    }
    __syncthreads();                 // x-frags visible

    // ---- x-proj: wave w = e-quarter (4 nt), BOTH row-tiles; 1-deep wb pipeline ----
    {
        float bv[4];
#pragma unroll
        for (int ne = 0; ne < 4; ne++) bv[ne] = bias[(w * 4 + ne) * 16 + c];
        f32x4 pacc[2][4];
#pragma unroll
        for (int rs = 0; rs < 2; rs++)
#pragma unroll
            for (int ne = 0; ne < 4; ne++) pacc[rs][ne] = (f32x4)0.f;
        f16x8 wbn[4];
#pragma unroll
        for (int ne = 0; ne < 4; ne++)
            wbn[ne] = *(const f16x8*)(Whf + ((size_t)(w * 4 + ne)) * 512 + L * 8);
#pragma unroll
        for (int kc = 0; kc < 8; kc++) {
            f16x8 wbc[4];
#pragma unroll
            for (int ne = 0; ne < 4; ne++) wbc[ne] = wbn[ne];
            if (kc < 7) {
#pragma unroll
                for (int ne = 0; ne < 4; ne++)
                    wbn[ne] = *(const f16x8*)(Whf + ((size_t)((kc + 1) * 16 + w * 4 + ne)) * 512 + L * 8);
            }
            f16x8 ah0 = *(const f16x8*)(lds + kc * 512 + L * 8);
            f16x8 ah1 = *(const f16x8*)(lds + (8 + kc) * 512 + L * 8);
            __builtin_amdgcn_sched_barrier(0);
#pragma unroll
            for (int ne = 0; ne < 4; ne++) {
                pacc[0][ne] = __builtin_amdgcn_mfma_f32_16x16x32_f16(ah0, wbc[ne], pacc[0][ne], 0, 0, 0);
                pacc[1][ne] = __builtin_amdgcn_mfma_f32_16x16x32_f16(ah1, wbc[ne], pacc[1][ne], 0, 0, 0);
            }
        }
        // scatter relu(acc+bias) f16 -> pfrag LDS [16K,32K) in A-frag layout.
        // e = (w*4+ne)*16+c; row = rs*16+quad*4+r; unit = rs*8+w*2+(ne>>1).
#pragma unroll
        for (int rs = 0; rs < 2; rs++)
#pragma unroll
            for (int ne = 0; ne < 4; ne++) {
#pragma unroll
                for (int r = 0; r < 4; r++) {
                    float v = fmaxf(pacc[rs][ne][r] + bv[ne], 0.f);
                    int off = 8192 + (rs * 8 + w * 2 + (ne >> 1)) * 512 +
                              ((ne & 1) * 2 + (c >> 3)) * 128 + (quad * 4 + r) * 8 + (c & 7);
                    lds[off] = f2h(v);
                }
            }
    }

    f32x4 sc[2][8];
#pragma unroll
    for (int rs = 0; rs < 2; rs++)
#pragma unroll
        for (int qt = 0; qt < 8; qt++) sc[rs][qt] = (f32x4)0.f;
    __syncthreads();                 // proj frags visible

    // ---- Phase A: 1-deep y-frag pipeline; B-frags from L2-resident ypf ----
    const ushort* pf = lds + 8192;   // proj A-frags
    const ushort* yb = ypf + (size_t)b * 256 * 512;
    {
        f16x8 bhn[8];
#pragma unroll
        for (int qt = 0; qt < 8; qt++)
            bhn[qt] = *(const f16x8*)(yb + (size_t)(w * 8 + qt) * 512 + L * 8);
#pragma unroll
        for (int kc = 0; kc < 8; kc++) {
            f16x8 bhc[8];
#pragma unroll
            for (int qt = 0; qt < 8; qt++) bhc[qt] = bhn[qt];
            if (kc < 7) {
#pragma unroll
                for (int qt = 0; qt < 8; qt++)
                    bhn[qt] = *(const f16x8*)(yb + ((size_t)(kc + 1) * 32 + w * 8 + qt) * 512 + L * 8);
            }
            f16x8 ah0 = *(const f16x8*)(pf + kc * 512 + L * 8);
            f16x8 ah1 = *(const f16x8*)(pf + (8 + kc) * 512 + L * 8);
            __builtin_amdgcn_sched_barrier(0);
#pragma unroll
            for (int qt = 0; qt < 8; qt++) {
                sc[0][qt] = __builtin_amdgcn_mfma_f32_16x16x32_f16(ah0, bhc[qt], sc[0][qt], 0, 0, 0);
                sc[1][qt] = __builtin_amdgcn_mfma_f32_16x16x32_f16(ah1, bhc[qt], sc[1][qt], 0, 0, 0);
            }
        }
    }

    // ---- Phase B: softmax; each wave holds a q-quarter of every row ----
    __syncthreads();                 // proj-frag reads done; lds reusable
    float* red  = (float*)lds;       // [32][4] partial max (x-frag region, dead)
    float* red2 = red + 128;         // [32][4] partial sum
    float inv[2][4];
#pragma unroll
    for (int rs = 0; rs < 2; rs++)
#pragma unroll
        for (int r = 0; r < 4; r++) {
            float pm = sc[rs][0][r];
#pragma unroll
            for (int qt = 1; qt < 8; qt++) pm = fmaxf(pm, sc[rs][qt][r]);
#pragma unroll
            for (int mask = 1; mask <= 8; mask <<= 1) pm = fmaxf(pm, __shfl_xor(pm, mask));
            if (c == 0) red[(rs * 16 + quad * 4 + r) * 4 + w] = pm;
        }
    __syncthreads();
#pragma unroll
    for (int rs = 0; rs < 2; rs++)
#pragma unroll
        for (int r = 0; r < 4; r++) {
            int row = rs * 16 + quad * 4 + r;
            float m = fmaxf(fmaxf(red[row * 4], red[row * 4 + 1]),
                            fmaxf(red[row * 4 + 2], red[row * 4 + 3]));
            float ps = 0.f;
#pragma unroll
            for (int qt = 0; qt < 8; qt++) {
                float e = __expf(sc[rs][qt][r] - m);
                sc[rs][qt][r] = e;
                ps += e;
            }
#pragma unroll
            for (int mask = 1; mask <= 8; mask <<= 1) ps += __shfl_xor(ps, mask);
            if (c == 0) red2[row * 4 + w] = ps;
        }
    __syncthreads();
#pragma unroll
    for (int rs = 0; rs < 2; rs++)
#pragma unroll
        for (int r = 0; r < 4; r++) {
            int row = rs * 16 + quad * 4 + r;
            inv[rs][r] = 1.f / (red2[row * 4] + red2[row * 4 + 1] +
                                red2[row * 4 + 2] + red2[row * 4 + 3]);
        }
    __syncthreads();                 // red/red2 reads done before alpha overwrites

    // alpha (f16) -> LDS [32 rows][512 q], xor-swizzled 8-elem chunks
#pragma unroll
    for (int rs = 0; rs < 2; rs++)
#pragma unroll
        for (int r = 0; r < 4; r++) {
            int m_loc = rs * 16 + quad * 4 + r;
            int swz = m_loc & 7;
            float iv = inv[rs][r];
#pragma unroll
            for (int qt = 0; qt < 8; qt++) {
                int q = w * 128 + qt * 16 + c;
                lds[m_loc * 512 + (((q >> 3) ^ swz) << 3) + (c & 7)] = f2h(sc[rs][qt][r] * iv);
            }
        }
    __syncthreads();

    // ---- Phase C: out = alpha(LDS) @ yf(global); pairwise kcq, 1-deep pipeline ----
    f32x4 o[2][4];
#pragma unroll
    for (int rs = 0; rs < 2; rs++)
#pragma unroll
        for (int dt = 0; dt < 4; dt++) o[rs][dt] = (f32x4)0.f;
    const int dh = w;
    const int swzA = c & 7;          // (rs*16+c)&7 == c&7
    {
        f16x8 bfn[8];
#pragma unroll
        for (int u = 0; u < 8; u++)
            bfn[u] = *(const f16x8*)(yf + (size_t)(b * 256 + (u >> 2) * 16 + dh * 4 + (u & 3)) * 512 + L * 8);
#pragma unroll
        for (int kp = 0; kp < 8; kp++) {       // pair kcq = 2*kp, 2*kp+1
            f16x8 bfc[8];
#pragma unroll
            for (int u = 0; u < 8; u++) bfc[u] = bfn[u];
            if (kp < 7) {
#pragma unroll
                for (int u = 0; u < 8; u++)
                    bfn[u] = *(const f16x8*)(yf + (size_t)(b * 256 + (2 * kp + 2 + (u >> 2)) * 16 + dh * 4 + (u & 3)) * 512 + L * 8);
            }
            f16x8 af[2][2];
#pragma unroll
            for (int h = 0; h < 2; h++) {
                int chunk = (2 * kp + h) * 4 + quad;
                af[h][0] = *(const f16x8*)(lds + c * 512 + ((chunk ^ swzA) << 3));
                af[h][1] = *(const f16x8*)(lds + (16 + c) * 512 + ((chunk ^ swzA) << 3));
            }
            __builtin_amdgcn_sched_barrier(0);
#pragma unroll
            for (int h = 0; h < 2; h++) {
#pragma unroll
                for (int dt = 0; dt < 4; dt++) {
                    o[0][dt] = __builtin_amdgcn_mfma_f32_16x16x32_f16(af[h][0], bfc[h * 4 + dt], o[0][dt], 0, 0, 0);
                    o[1][dt] = __builtin_amdgcn_mfma_f32_16x16x32_f16(af[h][1], bfc[h * 4 + dt], o[1][dt], 0, 0, 0);
                }
            }
        }
    }

    // ---- direct store (no exchange: each wave owns a d-quarter, full q summed) ----
#pragma unroll
    for (int rs = 0; rs < 2; rs++)
#pragma unroll
        for (int dt = 0; dt < 4; dt++)
#pragma unroll
            for (int r = 0; r < 4; r++) {
                int row = rs * 16 + quad * 4 + r;
                out[(size_t)(b * LP_ + m0 + row) * 256 + dh * 64 + dt * 16 + c] =
                    o[rs][dt][r];
            }
}

extern "C" void kernel_launch(void* const* d_in, const int* in_sizes, int n_in,
                              void* d_out, int out_size, void* d_ws, size_t ws_size,
                              hipStream_t stream) {
    const float* x    = (const float*)d_in[0];
    const float* y    = (const float*)d_in[1];
    const float* W    = (const float*)d_in[2];
    const float* bias = (const float*)d_in[3];
    float* out = (float*)d_out;

    char* ws = (char*)d_ws;
    size_t off = 0;
    ushort* Whf = (ushort*)(ws + off); off += (size_t)D_ * D_ * 2;          // 128KB
    ushort* yfb = (ushort*)(ws + off); off += (size_t)B_ * D_ * LQ_ * 2;    // 8MB
    ushort* ypf = (ushort*)(ws + off); off += (size_t)B_ * LQ_ * D_ * 2;    // 8MB

    k_prep<<<768, 256, 0, stream>>>(W, y, Whf, yfb);
    k_proj<<<256, 256, 0, stream>>>(y, Whf, bias, ypf);
    k_attn<<<B_ * 64, 256, 0, stream>>>(x, Whf, bias, ypf, yfb, out);
}